// Round 16
// baseline (771.586 us; speedup 1.0000x reference)
//
#include <hip/hip_runtime.h>
#include <math.h>

// ---------------------------------------------------------------------------
// N=64, L=128, W=256, D=384, H=8, E=48, NL=4, DFF=1536, rows = N*L = 8192
// GEMMs: bf16 MFMA 16x16x32, A [M][K] bf16 row-major, Bt [N][K] bf16.
// R16 = R15 + cnn stage-C quarter-K split (Bm 8 KB -> LDS ~25 KB ->
// 6 blocks/CU). Parallel-window structure preserved.
// ---------------------------------------------------------------------------

typedef float f32x4 __attribute__((ext_vector_type(4)));
typedef short bf16x8 __attribute__((ext_vector_type(8)));
typedef short s16x4 __attribute__((ext_vector_type(4)));

__device__ __forceinline__ short f2bf(float f) {
    union { float f; unsigned u; } c; c.f = f;
    unsigned r = (c.u + 0x7FFFu + ((c.u >> 16) & 1u)) >> 16;
    return (short)r;
}
__device__ __forceinline__ float bf2f(short s) {
    union { unsigned u; float f; } c;
    c.u = ((unsigned)(unsigned short)s) << 16;
    return c.f;
}

__device__ __forceinline__ void gload_lds16(const void* g, void* l) {
    __builtin_amdgcn_global_load_lds(
        (const __attribute__((address_space(1))) unsigned int*)g,
        (__attribute__((address_space(3))) unsigned int*)l,
        16, 0, 0);
}

// ---------------- positional encoding table: pe[l][d] ----------------------
__global__ __launch_bounds__(384) void pe_kernel(float* __restrict__ pe) {
    int l = blockIdx.x, d = threadIdx.x;
    int i2 = d >> 1;
    float ang = (float)l * expf(-(2.0f * (float)i2 / 384.0f) * 9.210340371976184f);
    pe[l * 384 + d] = (d & 1) ? cosf(ang) : sinf(ang);
}

// ---------------- weight convert+transpose: W fp32 [K][N] -> bf16 [N][K] ---
__global__ __launch_bounds__(256) void wcvt_kernel(
    const float* __restrict__ W, short* __restrict__ Wt, int K, int N,
    int dstOff, int srcZ, int dstZ)
{
    __shared__ float tile[32][33];
    int kb = blockIdx.x * 32, nb = blockIdx.y * 32;
    const float* Wp = W + (size_t)blockIdx.z * srcZ;
    short* Wtp = Wt + (size_t)blockIdx.z * dstZ + dstOff;
    int tx = threadIdx.x & 31, ty = threadIdx.x >> 5;
    #pragma unroll
    for (int r = ty; r < 32; r += 8)
        tile[r][tx] = Wp[(size_t)(kb + r) * N + nb + tx];
    __syncthreads();
    #pragma unroll
    for (int r = ty; r < 32; r += 8)
        Wtp[(size_t)(nb + r) * K + kb + tx] = f2bf(tile[tx][r]);
}

// ---------------- Wq/Wk/Wv -> WqkvT in one dispatch (z = layer*3+which) ----
__global__ __launch_bounds__(256) void qkvcvt_kernel(
    const float* __restrict__ Wq, const float* __restrict__ Wk,
    const float* __restrict__ Wv, short* __restrict__ WqkvT)
{
    __shared__ float tile[32][33];
    int kb = blockIdx.x * 32, nb = blockIdx.y * 32;
    int layer = blockIdx.z / 3, which = blockIdx.z - layer * 3;
    const float* Wp = (which == 0 ? Wq : (which == 1 ? Wk : Wv)) +
                      (size_t)layer * 147456;
    short* Wtp = WqkvT + (size_t)layer * 442368 + (size_t)which * 147456;
    int tx = threadIdx.x & 31, ty = threadIdx.x >> 5;
    #pragma unroll
    for (int r = ty; r < 32; r += 8)
        tile[r][tx] = Wp[(size_t)(kb + r) * 384 + nb + tx];
    __syncthreads();
    #pragma unroll
    for (int r = ty; r < 32; r += 8)
        Wtp[(size_t)(nb + r) * 384 + kb + tx] = f2bf(tile[tx][r]);
}

// ---------------- conv2 weights -> bf16 [c][kk], kk padded 112->128 --------
__global__ __launch_bounds__(256) void w2cvt_kernel(
    const float* __restrict__ w2, short* __restrict__ w2T)
{
    int idx = blockIdx.x * 256 + threadIdx.x;   // 64*128 = 8192
    int c = idx >> 7, kk = idx & 127;
    w2T[idx] = (kk < 112) ? f2bf(w2[c * 112 + kk]) : (short)0;
}

// ---------------- concatenated qkv bias: bqkv[l][1152] ---------------------
__global__ __launch_bounds__(384) void biascat_kernel(
    const float* __restrict__ bq, const float* __restrict__ bk,
    const float* __restrict__ bv, float* __restrict__ bqkv)
{
    int l = blockIdx.x, j = threadIdx.x;
    bqkv[l * 1152 + j] = bq[l * 384 + j];
    bqkv[l * 1152 + 384 + j] = bk[l * 384 + j];
    bqkv[l * 1152 + 768 + j] = bv[l * 384 + j];
}

// ---------------- fused CNN window encoder: 2 windows per block ------------
// Stage C quarter-K split: Bm[2][64*32] (8 KB) -> LDS ~25 KB -> 6 blocks/CU.
// Per pass: 1 b128 im2col write/window, 2 ds_reads + 8 MFMAs.
// Swizzle (4-slot rows): slot = s ^ (i&3) ^ ((i>>2)&3) -- 2-way free for
// both the write pattern and the frag reads.
__global__ __launch_bounds__(256) void cnn_kernel(
    const float* __restrict__ x,
    const float* __restrict__ w0, const float* __restrict__ b0,
    const float* __restrict__ w1, const float* __restrict__ b1,
    const short* __restrict__ w2T, const float* __restrict__ b2,
    short* __restrict__ feat)
{
    __shared__ float xs[2][256];
    __shared__ float p0[2][4][136];
    __shared__ float p1[2][16][65];
    __shared__ short Bm[2][64 * 32];    // im2col quarter-K, swizzled, 8 KB
    __shared__ float w1s[64][7];
    __shared__ float w0s[4][7];

    int tid = threadIdx.x;
    size_t win0 = (size_t)blockIdx.x * 2;
    int w = tid >> 6, lane = tid & 63;
    int cq = lane >> 4, cl = lane & 15;

    xs[0][tid] = x[win0 * 256 + tid];
    xs[1][tid] = x[(win0 + 1) * 256 + tid];
    if (tid < 28) ((float*)w0s)[tid] = w0[tid];
    if (tid < 64) {
        for (int k = 0; k < 7; ++k) w1s[tid][k] = w1[tid * 7 + k];
    }
    __syncthreads();

    // ---- stage A: conv0 (1->4) + relu + pool2 -> p0[wv][4][128] ----
    #pragma unroll
    for (int wv = 0; wv < 2; ++wv) {
        int c = tid & 3, p = tid >> 2;
        float bb = b0[c];
        #pragma unroll
        for (int t2 = 0; t2 < 2; ++t2) {
            int pp = p + 64 * t2;
            float rv[9];
            #pragma unroll
            for (int u = 0; u < 9; ++u) {
                int j = 2 * pp + u - 3;
                rv[u] = (j >= 0 && j < 256) ? xs[wv][j] : 0.f;
            }
            float a0 = bb, a1 = bb;
            #pragma unroll
            for (int k = 0; k < 7; ++k) {
                float ww = w0s[c][k];
                a0 = fmaf(ww, rv[k], a0);
                a1 = fmaf(ww, rv[k + 1], a1);
            }
            p0[wv][c][pp] = fmaxf(fmaxf(a0, a1), 0.f);
        }
    }
    __syncthreads();

    // ---- stage B: conv1 (4->16) + relu + pool2 -> p1[wv][16][64] ----
    #pragma unroll
    for (int wv = 0; wv < 2; ++wv) {
        int c = tid & 15;
        int i0 = (tid >> 4) * 8;
        float acc[8];
        float bb = b1[c];
        #pragma unroll
        for (int m = 0; m < 8; ++m) acc[m] = bb;
        #pragma unroll
        for (int ci = 0; ci < 4; ++ci) {
            float rv[14];
            #pragma unroll
            for (int u = 0; u < 14; ++u) {
                int j = i0 + u - 3;
                rv[u] = (j >= 0 && j < 128) ? p0[wv][ci][j] : 0.f;
            }
            #pragma unroll
            for (int k = 0; k < 7; ++k) {
                float ww = w1s[c * 4 + ci][k];
                #pragma unroll
                for (int m = 0; m < 8; ++m) acc[m] = fmaf(ww, rv[m + k], acc[m]);
            }
        }
        int po = i0 >> 1;
        #pragma unroll
        for (int m = 0; m < 4; ++m)
            p1[wv][c][po + m] = fmaxf(fmaxf(acc[2 * m], acc[2 * m + 1]), 0.f);
    }
    __syncthreads();

    // ---- stage C: four K-quarters; im2col(32 kk) -> MFMA accumulate ----
    f32x4 acc0[4], acc1[4];
    #pragma unroll
    for (int mt = 0; mt < 4; ++mt) {
        acc0[mt] = (f32x4){0.f, 0.f, 0.f, 0.f};
        acc1[mt] = (f32x4){0.f, 0.f, 0.f, 0.f};
    }
    int rr = w * 16 + cl;                // position row in Bm
    int rslot = cq ^ (rr & 3) ^ ((rr >> 2) & 3);
    #pragma unroll
    for (int kq = 0; kq < 4; ++kq) {
        // im2col fill for kk in [kq*32, kq*32+32): 1 b128 write per window
        #pragma unroll
        for (int wv = 0; wv < 2; ++wv) {
            int i_ = tid >> 2;
            int sg = tid & 3;                // slot 0..3, kk = kq*32+sg*8..+7
            bf16x8 pack;
            #pragma unroll
            for (int j = 0; j < 8; ++j) {
                int kk = kq * 32 + sg * 8 + j;
                int ci = (kk * 147) >> 10;   // kk/7 for kk<128
                int k = kk - ci * 7;
                int jp = i_ + k - 3;
                float v = (kk < 112 && jp >= 0 && jp < 64) ? p1[wv][ci][jp] : 0.f;
                pack[j] = f2bf(v);
            }
            int slot = sg ^ (i_ & 3) ^ ((i_ >> 2) & 3);
            *(bf16x8*)&Bm[wv][i_ * 32 + slot * 8] = pack;
        }
        __syncthreads();
        // MFMA both windows (K=32 -> one MFMA per mt per window)
        bf16x8 bfr0 = *(const bf16x8*)&Bm[0][rr * 32 + rslot * 8];
        bf16x8 bfr1 = *(const bf16x8*)&Bm[1][rr * 32 + rslot * 8];
        #pragma unroll
        for (int mt = 0; mt < 4; ++mt) {
            bf16x8 af = *(const bf16x8*)&w2T[(mt * 16 + cl) * 128 +
                                             kq * 32 + cq * 8];
            acc0[mt] = __builtin_amdgcn_mfma_f32_16x16x32_bf16(
                af, bfr0, acc0[mt], 0, 0, 0);
            acc1[mt] = __builtin_amdgcn_mfma_f32_16x16x32_bf16(
                af, bfr1, acc1[mt], 0, 0, 0);
        }
        __syncthreads();
    }

    // ---- epilogue: pool pairs via shfl, store bf16 ----
    #pragma unroll
    for (int wv = 0; wv < 2; ++wv) {
        short* fp = feat + (win0 + wv) * 2048;
        int iev = (w * 16 + cl) >> 1;
        #pragma unroll
        for (int mt = 0; mt < 4; ++mt) {
            #pragma unroll
            for (int rg = 0; rg < 4; ++rg) {
                float v = wv ? acc1[mt][rg] : acc0[mt][rg];
                float v2 = __shfl_xor(v, 1, 64);
                if ((cl & 1) == 0) {
                    int c = mt * 16 + cq * 4 + rg;
                    float pv = fmaxf(fmaxf(v, v2) + b2[c], 0.f);
                    fp[c * 32 + iev] = f2bf(pv);
                }
            }
        }
    }
}

// ---------------- bf16 MFMA GEMM (thin-N): BM=128, BN=64, double-buffered --
// EPI bits: 1=relu, 2=+resid(f32), 4=+pe, 8=write f32, 16=write bf16
template <int EPI>
__global__ __launch_bounds__(256) void gemm_bf16(
    const short* __restrict__ A, const short* __restrict__ Bt,
    const float* __restrict__ bias, const float* __restrict__ resid,
    const float* __restrict__ pe, float* __restrict__ outF,
    short* __restrict__ outB, int M, int N, int K)
{
    __shared__ short As[2][128 * 64];
    __shared__ short Bs[2][64 * 64];
    int tid = threadIdx.x;
    int w = tid >> 6, lane = tid & 63;
    int wm = w >> 1, wn = w & 1;
    int m0 = blockIdx.y * 128, n0 = blockIdx.x * 64;

    int rl = lane >> 3, sl = lane & 7;
    int cb = sl ^ rl;
    const short* aptr[4];
    const short* bptr[2];
    int arow[4], brow[2];
    #pragma unroll
    for (int l = 0; l < 4; ++l) {
        arow[l] = l * 32 + w * 8;
        aptr[l] = A + (size_t)(m0 + arow[l] + rl) * K + cb * 8;
    }
    #pragma unroll
    for (int l = 0; l < 2; ++l) {
        brow[l] = l * 32 + w * 8;
        bptr[l] = Bt + (size_t)(n0 + brow[l] + rl) * K + cb * 8;
    }

    int cq = lane >> 4, cl = lane & 15;
    f32x4 acc[4][2];
    #pragma unroll
    for (int mt = 0; mt < 4; ++mt)
        #pragma unroll
        for (int nt = 0; nt < 2; ++nt)
            acc[mt][nt] = (f32x4){0.f, 0.f, 0.f, 0.f};

    #pragma unroll
    for (int l = 0; l < 4; ++l) { gload_lds16(aptr[l], &As[0][arow[l] * 64]); aptr[l] += 64; }
    #pragma unroll
    for (int l = 0; l < 2; ++l) { gload_lds16(bptr[l], &Bs[0][brow[l] * 64]); bptr[l] += 64; }
    __syncthreads();

    int nk = K >> 6;
    for (int k = 0; k < nk; ++k) {
        int cur = k & 1;
        if (k + 1 < nk) {
            #pragma unroll
            for (int l = 0; l < 4; ++l) { gload_lds16(aptr[l], &As[cur ^ 1][arow[l] * 64]); aptr[l] += 64; }
            #pragma unroll
            for (int l = 0; l < 2; ++l) { gload_lds16(bptr[l], &Bs[cur ^ 1][brow[l] * 64]); bptr[l] += 64; }
        }
        #pragma unroll
        for (int s = 0; s < 2; ++s) {
            bf16x8 afr[4], bfr[2];
            #pragma unroll
            for (int mt = 0; mt < 4; ++mt) {
                int r = wm * 64 + mt * 16 + cl;
                int slot = (s * 4 + cq) ^ (r & 7);
                afr[mt] = *(const bf16x8*)&As[cur][r * 64 + slot * 8];
            }
            #pragma unroll
            for (int nt = 0; nt < 2; ++nt) {
                int r = wn * 32 + nt * 16 + cl;
                int slot = (s * 4 + cq) ^ (r & 7);
                bfr[nt] = *(const bf16x8*)&Bs[cur][r * 64 + slot * 8];
            }
            #pragma unroll
            for (int mt = 0; mt < 4; ++mt)
                #pragma unroll
                for (int nt = 0; nt < 2; ++nt)
                    acc[mt][nt] = __builtin_amdgcn_mfma_f32_16x16x32_bf16(
                        afr[mt], bfr[nt], acc[mt][nt], 0, 0, 0);
        }
        __syncthreads();
    }

    #pragma unroll
    for (int mt = 0; mt < 4; ++mt) {
        #pragma unroll
        for (int nt = 0; nt < 2; ++nt) {
            int col = n0 + wn * 32 + nt * 16 + cl;
            float bb = bias[col];
            #pragma unroll
            for (int rg = 0; rg < 4; ++rg) {
                int row = m0 + wm * 64 + mt * 16 + cq * 4 + rg;
                float v = acc[mt][nt][rg] + bb;
                if (EPI & 1) v = fmaxf(v, 0.f);
                if (EPI & 4) v += pe[(row & 127) * 384 + col];
                if (EPI & 2) v += resid[(size_t)row * N + col];
                if (EPI & 8) outF[(size_t)row * N + col] = v;
                if (EPI & 16) outB[(size_t)row * N + col] = f2bf(v);
            }
        }
    }
}

// ---------------- bf16 MFMA GEMM (wide-N): BM=128, BN=128, BK=32 dbuf ------
template <int EPI>
__global__ __launch_bounds__(256) void gemm_bf16_wide(
    const short* __restrict__ A, const short* __restrict__ Bt,
    const float* __restrict__ bias, float* __restrict__ outF,
    short* __restrict__ outB, int M, int N, int K)
{
    __shared__ short As[2][128 * 32];
    __shared__ short Bs[2][128 * 32];
    int tid = threadIdx.x;
    int w = tid >> 6, lane = tid & 63;
    int wm = w >> 1, wn = w & 1;
    int m0 = blockIdx.y * 128, n0 = blockIdx.x * 128;

    int rl = lane >> 2, sl = lane & 3;
    int cb = sl ^ (rl & 3) ^ ((rl >> 2) & 3);
    const short* aptr[2];
    const short* bptr[2];
    int srow[2];
    #pragma unroll
    for (int l = 0; l < 2; ++l) {
        srow[l] = w * 32 + l * 16;
        aptr[l] = A + (size_t)(m0 + srow[l] + rl) * K + cb * 8;
        bptr[l] = Bt + (size_t)(n0 + srow[l] + rl) * K + cb * 8;
    }

    int cq = lane >> 4, cl = lane & 15;
    f32x4 acc[4][4];
    #pragma unroll
    for (int mt = 0; mt < 4; ++mt)
        #pragma unroll
        for (int nt = 0; nt < 4; ++nt)
            acc[mt][nt] = (f32x4){0.f, 0.f, 0.f, 0.f};

    #pragma unroll
    for (int l = 0; l < 2; ++l) {
        gload_lds16(aptr[l], &As[0][srow[l] * 32]);
        gload_lds16(bptr[l], &Bs[0][srow[l] * 32]);
        aptr[l] += 32; bptr[l] += 32;
    }
    __syncthreads();

    int nk = K >> 5;
    for (int k = 0; k < nk; ++k) {
        int cur = k & 1;
        if (k + 1 < nk) {
            #pragma unroll
            for (int l = 0; l < 2; ++l) {
                gload_lds16(aptr[l], &As[cur ^ 1][srow[l] * 32]);
                gload_lds16(bptr[l], &Bs[cur ^ 1][srow[l] * 32]);
                aptr[l] += 32; bptr[l] += 32;
            }
        }
        bf16x8 afr[4], bfr[4];
        #pragma unroll
        for (int mt = 0; mt < 4; ++mt) {
            int r = wm * 64 + mt * 16 + cl;
            int slot = cq ^ (r & 3) ^ ((r >> 2) & 3);
            afr[mt] = *(const bf16x8*)&As[cur][r * 32 + slot * 8];
        }
        #pragma unroll
        for (int nt = 0; nt < 4; ++nt) {
            int r = wn * 64 + nt * 16 + cl;
            int slot = cq ^ (r & 3) ^ ((r >> 2) & 3);
            bfr[nt] = *(const bf16x8*)&Bs[cur][r * 32 + slot * 8];
        }
        #pragma unroll
        for (int mt = 0; mt < 4; ++mt)
            #pragma unroll
            for (int nt = 0; nt < 4; ++nt)
                acc[mt][nt] = __builtin_amdgcn_mfma_f32_16x16x32_bf16(
                    afr[mt], bfr[nt], acc[mt][nt], 0, 0, 0);
        __syncthreads();
    }

    #pragma unroll
    for (int mt = 0; mt < 4; ++mt) {
        #pragma unroll
        for (int nt = 0; nt < 4; ++nt) {
            int col = n0 + wn * 64 + nt * 16 + cl;
            float bb = bias[col];
            #pragma unroll
            for (int rg = 0; rg < 4; ++rg) {
                int row = m0 + wm * 64 + mt * 16 + cq * 4 + rg;
                float v = acc[mt][nt][rg] + bb;
                if (EPI & 1) v = fmaxf(v, 0.f);
                if (EPI & 8) outF[(size_t)row * N + col] = v;
                if (EPI & 16) outB[(size_t)row * N + col] = f2bf(v);
            }
        }
    }
}

// ---------------- fused GEMM + bias + residual + LayerNorm -----------------
// BM=16, BN=384, BK=64 -> grid 512. (BK=32 regressed in R13.)
__global__ __launch_bounds__(256) void gemm_ln(
    const short* __restrict__ A, const short* __restrict__ Bt,
    const float* __restrict__ bias, const float* resid,
    const float* __restrict__ g, const float* __restrict__ be,
    float* t, short* __restrict__ tb, int K)
{
    __shared__ __align__(16) char smem[51200];
    short* As = (short*)smem;              // 16 x 64 bf16 = 2 KB
    short* Bs = (short*)(smem + 2048);     // 384 x 64 bf16 = 48 KB

    int tid = threadIdx.x;
    int w = tid >> 6, lane = tid & 63;
    int m0 = blockIdx.x * 16;
    int rl = lane >> 3, sl = lane & 7;
    int cb = sl ^ rl;

    const short* aptr = A + (size_t)(m0 + w * 8 + rl) * K + cb * 8;
    const short* bptr[12];
    #pragma unroll
    for (int l = 0; l < 12; ++l)
        bptr[l] = Bt + (size_t)(w * 96 + l * 8 + rl) * K + cb * 8;

    int cq = lane >> 4, cl = lane & 15;
    f32x4 acc[6];
    #pragma unroll
    for (int nt = 0; nt < 6; ++nt) acc[nt] = (f32x4){0.f, 0.f, 0.f, 0.f};

    for (int k0 = 0; k0 < K; k0 += 64) {
        if (w < 2) {
            gload_lds16(aptr, &As[(w * 8) * 64]);
            aptr += 64;
        }
        #pragma unroll
        for (int l = 0; l < 12; ++l) {
            gload_lds16(bptr[l], &Bs[(w * 96 + l * 8) * 64]);
            bptr[l] += 64;
        }
        __syncthreads();
        #pragma unroll
        for (int s = 0; s < 2; ++s) {
            bf16x8 afr, bfr[6];
            {
                int r = cl;
                int slot = (s * 4 + cq) ^ (r & 7);
                afr = *(const bf16x8*)&As[r * 64 + slot * 8];
            }
            #pragma unroll
            for (int nt = 0; nt < 6; ++nt) {
                int r = w * 96 + nt * 16 + cl;
                int slot = (s * 4 + cq) ^ (r & 7);
                bfr[nt] = *(const bf16x8*)&Bs[r * 64 + slot * 8];
            }
            #pragma unroll
            for (int nt = 0; nt < 6; ++nt)
                acc[nt] = __builtin_amdgcn_mfma_f32_16x16x32_bf16(
                    afr, bfr[nt], acc[nt], 0, 0, 0);
        }
        __syncthreads();
    }

    // ---- epilogue: y = acc + bias + resid -> LDS (16 x 388 f32) ----
    float* yb = (float*)smem;
    #pragma unroll
    for (int nt = 0; nt < 6; ++nt) {
        int col = w * 96 + nt * 16 + cl;
        float bb = bias[col];
        #pragma unroll
        for (int rg = 0; rg < 4; ++rg) {
            int rloc = cq * 4 + rg;
            yb[rloc * 388 + col] =
                acc[nt][rg] + bb + resid[(size_t)(m0 + rloc) * 384 + col];
        }
    }
    __syncthreads();

    // ---- LayerNorm: 16 threads per row ----
    int rloc = tid >> 4, sub = tid & 15;
    f32x4 vals[6];
    float s = 0.f, s2 = 0.f;
    #pragma unroll
    for (int m = 0; m < 6; ++m) {
        f32x4 vv = *(const f32x4*)&yb[rloc * 388 + m * 64 + sub * 4];
        vals[m] = vv;
        #pragma unroll
        for (int j = 0; j < 4; ++j) {
            s += vv[j];
            s2 = fmaf(vv[j], vv[j], s2);
        }
    }
    s += __shfl_xor(s, 1, 64);  s2 += __shfl_xor(s2, 1, 64);
    s += __shfl_xor(s, 2, 64);  s2 += __shfl_xor(s2, 2, 64);
    s += __shfl_xor(s, 4, 64);  s2 += __shfl_xor(s2, 4, 64);
    s += __shfl_xor(s, 8, 64);  s2 += __shfl_xor(s2, 8, 64);
    float mean = s * (1.f / 384.f);
    float var = s2 * (1.f / 384.f) - mean * mean;
    float inv = rsqrtf(var + 1e-5f);

    size_t ro = (size_t)(m0 + rloc) * 384;
    #pragma unroll
    for (int m = 0; m < 6; ++m) {
        int c0 = m * 64 + sub * 4;
        f32x4 gg = *(const f32x4*)&g[c0];
        f32x4 bb = *(const f32x4*)&be[c0];
        f32x4 ov;
        s16x4 ob2;
        #pragma unroll
        for (int j = 0; j < 4; ++j) {
            float v = (vals[m][j] - mean) * inv * gg[j] + bb[j];
            ov[j] = v;
            ob2[j] = f2bf(v);
        }
        *(f32x4*)&t[ro + c0] = ov;
        *(s16x4*)&tb[ro + c0] = ob2;
    }
}

// ---------------- fused attention per (n,h): split-E x2, 256 threads -------
__global__ __launch_bounds__(256) void attn_kernel(
    const short* __restrict__ qkv, short* __restrict__ o)
{
    __shared__ f32x4 Ks[128][12];
    __shared__ f32x4 Vs[128][12];
    int tid = threadIdx.x;
    int n = blockIdx.x >> 3, h = blockIdx.x & 7;
    size_t base = (size_t)n * 128 * 1152 + (size_t)h * 48;
    const short* kp = qkv + base + 384;
    const short* vp = qkv + base + 768;
    for (int i = tid; i < 1536; i += 256) {
        int s = i / 12, e4 = i - s * 12;
        s16x4 kv = *(const s16x4*)(kp + (size_t)s * 1152 + e4 * 4);
        s16x4 vv = *(const s16x4*)(vp + (size_t)s * 1152 + e4 * 4);
        f32x4 kf, vf;
        #pragma unroll
        for (int j = 0; j < 4; ++j) { kf[j] = bf2f(kv[j]); vf[j] = bf2f(vv[j]); }
        Ks[s][e4] = kf;
        Vs[s][e4] = vf;
    }
    const float temp = 0.14433756729740643f;  // 1/sqrt(48)
    int r = tid >> 1;
    int h2 = tid & 1;
    int eb0 = h2 * 6;
    float qr[24];
    {
        const short* qp = qkv + base + (size_t)r * 1152 + h2 * 24;
        #pragma unroll
        for (int e4 = 0; e4 < 6; ++e4) {
            s16x4 qv = *(const s16x4*)(qp + e4 * 4);
            #pragma unroll
            for (int j = 0; j < 4; ++j) qr[e4 * 4 + j] = bf2f(qv[j]) * temp;
        }
    }
    __syncthreads();

    float m = -1e30f, denom = 0.f;
    f32x4 acc[6];
    #pragma unroll
    for (int e = 0; e < 6; ++e) acc[e] = (f32x4){0.f, 0.f, 0.f, 0.f};

    for (int s0 = 0; s0 < 128; s0 += 8) {
        float sc[8];
        #pragma unroll
        for (int u = 0; u < 8; ++u) {
            float t0 = 0.f;
            #pragma unroll
            for (int e = 0; e < 6; ++e) {
                f32x4 kk = Ks[s0 + u][eb0 + e];
                t0 = fmaf(qr[e * 4 + 0], kk[0], t0);
                t0 = fmaf(qr[e * 4 + 1], kk[1], t0);
                t0 = fmaf(qr[e * 4 + 2], kk[2], t0);
                t0 = fmaf(qr[e * 4 + 3], kk[3], t0);
            }
            sc[u] = t0 + __shfl_xor(t0, 1, 64);
        }
        float cmax = sc[0];
        #pragma unroll
        for (int u = 1; u < 8; ++u) cmax = fmaxf(cmax, sc[u]);
        float nm = fmaxf(m, cmax);
        float alpha = __expf(m - nm);
        m = nm;
        float p[8];
        float ps = 0.f;
        #pragma unroll
        for (int u = 0; u < 8; ++u) { p[u] = __expf(sc[u] - nm); ps += p[u]; }
        denom = denom * alpha + ps;
        #pragma unroll
        for (int e = 0; e < 6; ++e) {
            f32x4 a = acc[e];
            a[0] *= alpha; a[1] *= alpha; a[2] *= alpha; a[3] *= alpha;
            #pragma unroll
            for (int u = 0; u < 8; ++u) {
                f32x4 vv = Vs[s0 + u][eb0 + e];
                a[0] = fmaf(p[u], vv[0], a[0]);
                a[1] = fmaf(p[u], vv[1], a[1]);
                a[2] = fmaf(p[u], vv[2], a[2]);
                a[3] = fmaf(p[u], vv[3], a[3]);
            }
            acc[e] = a;
        }
    }
    float inv = 1.f / denom;
    short* op = o + ((size_t)n * 128 + r) * 384 + h * 48 + h2 * 24;
    #pragma unroll
    for (int e = 0; e < 6; ++e) {
        s16x4 ov;
        #pragma unroll
        for (int j = 0; j < 4; ++j) ov[j] = f2bf(acc[e][j] * inv);
        *(s16x4*)(op + e * 4) = ov;
    }
}

// ---------------- classifier head ------------------------------------------
__global__ __launch_bounds__(384) void head_kernel(
    const float* __restrict__ t, const float* __restrict__ cls_w,
    const float* __restrict__ cls_b, float* __restrict__ out)
{
    int n = blockIdx.x, d = threadIdx.x;
    float s = 0.f;
    for (int l = 0; l < 128; ++l) s += t[((size_t)n * 128 + l) * 384 + d];
    float p = s * (1.f / 128.f) * cls_w[d];
    #pragma unroll
    for (int off = 32; off > 0; off >>= 1) p += __shfl_xor(p, off, 64);
    __shared__ float red[6];
    if ((threadIdx.x & 63) == 0) red[threadIdx.x >> 6] = p;
    __syncthreads();
    if (threadIdx.x == 0) {
        float tot = red[0] + red[1] + red[2] + red[3] + red[4] + red[5];
        out[n] = tot + cls_b[0];
    }
}

// ---------------------------------------------------------------------------
extern "C" void kernel_launch(void* const* d_in, const int* in_sizes, int n_in,
                              void* d_out, int out_size, void* d_ws, size_t ws_size,
                              hipStream_t stream) {
    (void)n_in; (void)out_size; (void)ws_size;
    const float* x   = (const float*)d_in[0];
    const float* cw0 = (const float*)d_in[1];
    const float* cb0 = (const float*)d_in[2];
    const float* cw1 = (const float*)d_in[3];
    const float* cb1 = (const float*)d_in[4];
    const float* cw2 = (const float*)d_in[5];
    const float* cb2 = (const float*)d_in[6];
    const float* ew  = (const float*)d_in[7];
    const float* eb  = (const float*)d_in[8];
    bool dict_order = (in_sizes[10] == 589824);
    const float *Wq, *Wk, *Wv, *Wo, *W1, *W2, *bq, *bk, *bv, *bo, *b1, *b2;
    if (dict_order) {
        Wq = (const float*)d_in[9];  Wk = (const float*)d_in[10];
        Wv = (const float*)d_in[11]; Wo = (const float*)d_in[12];
        W1 = (const float*)d_in[13]; W2 = (const float*)d_in[14];
        bq = (const float*)d_in[15]; bk = (const float*)d_in[16];
        bv = (const float*)d_in[17]; bo = (const float*)d_in[18];
        b1 = (const float*)d_in[19]; b2 = (const float*)d_in[20];
    } else {
        Wq = (const float*)d_in[9];  bq = (const float*)d_in[10];
        Wk = (const float*)d_in[11]; bk = (const float*)d_in[12];
        Wv = (const float*)d_in[13]; bv = (const float*)d_in[14];
        Wo = (const float*)d_in[15]; bo = (const float*)d_in[16];
        W1 = (const float*)d_in[17]; b1 = (const float*)d_in[18];
        W2 = (const float*)d_in[19]; b2 = (const float*)d_in[20];
    }
    const float* g1  = (const float*)d_in[21];
    const float* be1 = (const float*)d_in[22];
    const float* g2  = (const float*)d_in[23];
    const float* be2 = (const float*)d_in[24];
    const float* clw = (const float*)d_in[25];
    const float* clb = (const float*)d_in[26];

    // ---- workspace layout (bytes) ----
    char* wp = (char*)d_ws;
    float* pe    = (float*)wp; wp += 196608;      // 128*384 f32
    short* featb = (short*)wp; wp += 33554432;    // 8192*2048 bf16 (reused as FFN hidden)
    float* t     = (float*)wp; wp += 12582912;    // 8192*384 f32
    short* tb    = (short*)wp; wp += 6291456;     // 8192*384 bf16
    short* qkvb  = (short*)wp; wp += 18874368;    // 8192*1152 bf16
    short* ob    = (short*)wp; wp += 6291456;     // 8192*384 bf16 (attn out)
    short* ewT   = (short*)wp; wp += 1572864;     // 384 x 2048
    short* WqkvT = (short*)wp; wp += 3538944;     // 4 x 1152 x 384
    short* WoT   = (short*)wp; wp += 1179648;     // 4 x 384 x 384
    short* W1T   = (short*)wp; wp += 4718592;     // 4 x 1536 x 384
    short* W2T   = (short*)wp; wp += 4718592;     // 4 x 384 x 1536
    float* bqkv  = (float*)wp; wp += 18432;       // 4 x 1152 f32
    short* w2T   = (short*)wp; wp += 16384;       // 64 x 128 bf16 (conv2)
    short* hb    = featb;                         // FFN hidden 8192*1536 bf16

    const int ROWS = 8192;

    pe_kernel<<<128, 384, 0, stream>>>(pe);
    wcvt_kernel<<<dim3(64, 12, 1), 256, 0, stream>>>(ew, ewT, 2048, 384, 0, 0, 0);
    qkvcvt_kernel<<<dim3(12, 12, 12), 256, 0, stream>>>(Wq, Wk, Wv, WqkvT);
    wcvt_kernel<<<dim3(12, 12, 4), 256, 0, stream>>>(Wo, WoT, 384, 384, 0, 147456, 147456);
    wcvt_kernel<<<dim3(12, 48, 4), 256, 0, stream>>>(W1, W1T, 384, 1536, 0, 589824, 589824);
    wcvt_kernel<<<dim3(48, 12, 4), 256, 0, stream>>>(W2, W2T, 1536, 384, 0, 589824, 589824);
    biascat_kernel<<<4, 384, 0, stream>>>(bq, bk, bv, bqkv);
    w2cvt_kernel<<<32, 256, 0, stream>>>(cw2, w2T);
    cnn_kernel<<<4096, 256, 0, stream>>>(x, cw0, cb0, cw1, cb1, w2T, cb2, featb);

    // t/tb = relu(feat @ ew + eb) + pe
    gemm_bf16<29><<<dim3(6, 64), 256, 0, stream>>>(featb, ewT, eb, nullptr, pe,
                                                   t, tb, ROWS, 384, 2048);
    for (int i = 0; i < 4; ++i) {
        const short* WqkvTi = WqkvT + (size_t)i * 442368;
        const short* WoTi = WoT + (size_t)i * 147456;
        const short* W1Ti = W1T + (size_t)i * 589824;
        const short* W2Ti = W2T + (size_t)i * 589824;
        gemm_bf16_wide<16><<<dim3(9, 64), 256, 0, stream>>>(tb, WqkvTi,
            bqkv + i * 1152, nullptr, qkvb, ROWS, 1152, 384);
        attn_kernel<<<512, 256, 0, stream>>>(qkvb, ob);
        // t/tb = LN(o @ Wo + bo + t)
        gemm_ln<<<512, 256, 0, stream>>>(ob, WoTi, bo + i * 384, t,
            g1 + i * 384, be1 + i * 384, t, tb, 384);
        // hidden = relu(t @ W1 + b1)
        gemm_bf16_wide<17><<<dim3(12, 64), 256, 0, stream>>>(tb, W1Ti,
            b1 + i * 1536, nullptr, hb, ROWS, 1536, 384);
        // t/tb = LN(hidden @ W2 + b2 + t)
        gemm_ln<<<512, 256, 0, stream>>>(hb, W2Ti, b2 + i * 384, t,
            g2 + i * 384, be2 + i * 384, t, tb, 1536);
    }
    head_kernel<<<64, 384, 0, stream>>>(t, clw, clb, (float*)d_out);
}

// Round 17
// 770.088 us; speedup vs baseline: 1.0019x; 1.0019x over previous
//
#include <hip/hip_runtime.h>
#include <math.h>

// ---------------------------------------------------------------------------
// N=64, L=128, W=256, D=384, H=8, E=48, NL=4, DFF=1536, rows = N*L = 8192
// GEMMs: bf16 MFMA 16x16x32, A [M][K] bf16 row-major, Bt [N][K] bf16.
// R17 = exact revert to R15 (session best, 770.5 us). R16's quarter-K cnn
// split regressed (barrier frequency > occupancy gain); half-K split is the
// measured optimum of that trade (R12 107 / R15 100 / R16 118 us).
// ---------------------------------------------------------------------------

typedef float f32x4 __attribute__((ext_vector_type(4)));
typedef short bf16x8 __attribute__((ext_vector_type(8)));
typedef short s16x4 __attribute__((ext_vector_type(4)));

__device__ __forceinline__ short f2bf(float f) {
    union { float f; unsigned u; } c; c.f = f;
    unsigned r = (c.u + 0x7FFFu + ((c.u >> 16) & 1u)) >> 16;
    return (short)r;
}
__device__ __forceinline__ float bf2f(short s) {
    union { unsigned u; float f; } c;
    c.u = ((unsigned)(unsigned short)s) << 16;
    return c.f;
}

__device__ __forceinline__ void gload_lds16(const void* g, void* l) {
    __builtin_amdgcn_global_load_lds(
        (const __attribute__((address_space(1))) unsigned int*)g,
        (__attribute__((address_space(3))) unsigned int*)l,
        16, 0, 0);
}

// ---------------- positional encoding table: pe[l][d] ----------------------
__global__ __launch_bounds__(384) void pe_kernel(float* __restrict__ pe) {
    int l = blockIdx.x, d = threadIdx.x;
    int i2 = d >> 1;
    float ang = (float)l * expf(-(2.0f * (float)i2 / 384.0f) * 9.210340371976184f);
    pe[l * 384 + d] = (d & 1) ? cosf(ang) : sinf(ang);
}

// ---------------- weight convert+transpose: W fp32 [K][N] -> bf16 [N][K] ---
__global__ __launch_bounds__(256) void wcvt_kernel(
    const float* __restrict__ W, short* __restrict__ Wt, int K, int N,
    int dstOff, int srcZ, int dstZ)
{
    __shared__ float tile[32][33];
    int kb = blockIdx.x * 32, nb = blockIdx.y * 32;
    const float* Wp = W + (size_t)blockIdx.z * srcZ;
    short* Wtp = Wt + (size_t)blockIdx.z * dstZ + dstOff;
    int tx = threadIdx.x & 31, ty = threadIdx.x >> 5;
    #pragma unroll
    for (int r = ty; r < 32; r += 8)
        tile[r][tx] = Wp[(size_t)(kb + r) * N + nb + tx];
    __syncthreads();
    #pragma unroll
    for (int r = ty; r < 32; r += 8)
        Wtp[(size_t)(nb + r) * K + kb + tx] = f2bf(tile[tx][r]);
}

// ---------------- Wq/Wk/Wv -> WqkvT in one dispatch (z = layer*3+which) ----
__global__ __launch_bounds__(256) void qkvcvt_kernel(
    const float* __restrict__ Wq, const float* __restrict__ Wk,
    const float* __restrict__ Wv, short* __restrict__ WqkvT)
{
    __shared__ float tile[32][33];
    int kb = blockIdx.x * 32, nb = blockIdx.y * 32;
    int layer = blockIdx.z / 3, which = blockIdx.z - layer * 3;
    const float* Wp = (which == 0 ? Wq : (which == 1 ? Wk : Wv)) +
                      (size_t)layer * 147456;
    short* Wtp = WqkvT + (size_t)layer * 442368 + (size_t)which * 147456;
    int tx = threadIdx.x & 31, ty = threadIdx.x >> 5;
    #pragma unroll
    for (int r = ty; r < 32; r += 8)
        tile[r][tx] = Wp[(size_t)(kb + r) * 384 + nb + tx];
    __syncthreads();
    #pragma unroll
    for (int r = ty; r < 32; r += 8)
        Wtp[(size_t)(nb + r) * 384 + kb + tx] = f2bf(tile[tx][r]);
}

// ---------------- conv2 weights -> bf16 [c][kk], kk padded 112->128 --------
__global__ __launch_bounds__(256) void w2cvt_kernel(
    const float* __restrict__ w2, short* __restrict__ w2T)
{
    int idx = blockIdx.x * 256 + threadIdx.x;   // 64*128 = 8192
    int c = idx >> 7, kk = idx & 127;
    w2T[idx] = (kk < 112) ? f2bf(w2[c * 112 + kk]) : (short)0;
}

// ---------------- concatenated qkv bias: bqkv[l][1152] ---------------------
__global__ __launch_bounds__(384) void biascat_kernel(
    const float* __restrict__ bq, const float* __restrict__ bk,
    const float* __restrict__ bv, float* __restrict__ bqkv)
{
    int l = blockIdx.x, j = threadIdx.x;
    bqkv[l * 1152 + j] = bq[l * 384 + j];
    bqkv[l * 1152 + 384 + j] = bk[l * 384 + j];
    bqkv[l * 1152 + 768 + j] = bv[l * 384 + j];
}

// ---------------- fused CNN window encoder: 2 windows per block ------------
// Stage C half-K split: Bm[2][64*64] (16 KB) filled/consumed in two kh
// passes with persistent accumulators -> LDS ~33.3 KB -> 4 blocks/CU.
// Windows stay PARALLEL (R13's serialization regressed); quarter-K split
// also regressed (R16: barrier frequency > occupancy).
__global__ __launch_bounds__(256) void cnn_kernel(
    const float* __restrict__ x,
    const float* __restrict__ w0, const float* __restrict__ b0,
    const float* __restrict__ w1, const float* __restrict__ b1,
    const short* __restrict__ w2T, const float* __restrict__ b2,
    short* __restrict__ feat)
{
    __shared__ float xs[2][256];
    __shared__ float p0[2][4][136];
    __shared__ float p1[2][16][65];
    __shared__ short Bm[2][64 * 64];    // im2col half-K, swizzled, 16 KB
    __shared__ float w1s[64][7];
    __shared__ float w0s[4][7];

    int tid = threadIdx.x;
    size_t win0 = (size_t)blockIdx.x * 2;
    int w = tid >> 6, lane = tid & 63;
    int cq = lane >> 4, cl = lane & 15;

    xs[0][tid] = x[win0 * 256 + tid];
    xs[1][tid] = x[(win0 + 1) * 256 + tid];
    if (tid < 28) ((float*)w0s)[tid] = w0[tid];
    if (tid < 64) {
        for (int k = 0; k < 7; ++k) w1s[tid][k] = w1[tid * 7 + k];
    }
    __syncthreads();

    // ---- stage A: conv0 (1->4) + relu + pool2 -> p0[wv][4][128] ----
    #pragma unroll
    for (int wv = 0; wv < 2; ++wv) {
        int c = tid & 3, p = tid >> 2;
        float bb = b0[c];
        #pragma unroll
        for (int t2 = 0; t2 < 2; ++t2) {
            int pp = p + 64 * t2;
            float rv[9];
            #pragma unroll
            for (int u = 0; u < 9; ++u) {
                int j = 2 * pp + u - 3;
                rv[u] = (j >= 0 && j < 256) ? xs[wv][j] : 0.f;
            }
            float a0 = bb, a1 = bb;
            #pragma unroll
            for (int k = 0; k < 7; ++k) {
                float ww = w0s[c][k];
                a0 = fmaf(ww, rv[k], a0);
                a1 = fmaf(ww, rv[k + 1], a1);
            }
            p0[wv][c][pp] = fmaxf(fmaxf(a0, a1), 0.f);
        }
    }
    __syncthreads();

    // ---- stage B: conv1 (4->16) + relu + pool2 -> p1[wv][16][64] ----
    #pragma unroll
    for (int wv = 0; wv < 2; ++wv) {
        int c = tid & 15;
        int i0 = (tid >> 4) * 8;
        float acc[8];
        float bb = b1[c];
        #pragma unroll
        for (int m = 0; m < 8; ++m) acc[m] = bb;
        #pragma unroll
        for (int ci = 0; ci < 4; ++ci) {
            float rv[14];
            #pragma unroll
            for (int u = 0; u < 14; ++u) {
                int j = i0 + u - 3;
                rv[u] = (j >= 0 && j < 128) ? p0[wv][ci][j] : 0.f;
            }
            #pragma unroll
            for (int k = 0; k < 7; ++k) {
                float ww = w1s[c * 4 + ci][k];
                #pragma unroll
                for (int m = 0; m < 8; ++m) acc[m] = fmaf(ww, rv[m + k], acc[m]);
            }
        }
        int po = i0 >> 1;
        #pragma unroll
        for (int m = 0; m < 4; ++m)
            p1[wv][c][po + m] = fmaxf(fmaxf(acc[2 * m], acc[2 * m + 1]), 0.f);
    }
    __syncthreads();

    // ---- stage C: two K-halves; im2col(64 kk) -> MFMA accumulate ----
    f32x4 acc0[4], acc1[4];
    #pragma unroll
    for (int mt = 0; mt < 4; ++mt) {
        acc0[mt] = (f32x4){0.f, 0.f, 0.f, 0.f};
        acc1[mt] = (f32x4){0.f, 0.f, 0.f, 0.f};
    }
    int rr = w * 16 + cl;                // position row in Bm
    #pragma unroll
    for (int kh = 0; kh < 2; ++kh) {
        // im2col fill for kk in [kh*64, kh*64+64): 2 b128 writes per window
        #pragma unroll
        for (int wv = 0; wv < 2; ++wv) {
            int i_ = tid >> 2;
            int sg = tid & 3;
            #pragma unroll
            for (int it = 0; it < 2; ++it) {
                int s = sg + it * 4;         // slot 0..7
                bf16x8 pack;
                #pragma unroll
                for (int j = 0; j < 8; ++j) {
                    int kk = kh * 64 + s * 8 + j;
                    int ci = (kk * 147) >> 10;   // kk/7 for kk<128
                    int k = kk - ci * 7;
                    int jp = i_ + k - 3;
                    float v = (kk < 112 && jp >= 0 && jp < 64) ? p1[wv][ci][jp] : 0.f;
                    pack[j] = f2bf(v);
                }
                int slot = s ^ (i_ & 7);
                *(bf16x8*)&Bm[wv][i_ * 64 + slot * 8] = pack;
            }
        }
        __syncthreads();
        // MFMA both windows
        #pragma unroll
        for (int s = 0; s < 2; ++s) {
            int slot = (s * 4 + cq) ^ (rr & 7);
            bf16x8 bfr0 = *(const bf16x8*)&Bm[0][rr * 64 + slot * 8];
            bf16x8 bfr1 = *(const bf16x8*)&Bm[1][rr * 64 + slot * 8];
            #pragma unroll
            for (int mt = 0; mt < 4; ++mt) {
                bf16x8 af = *(const bf16x8*)&w2T[(mt * 16 + cl) * 128 +
                                                 kh * 64 + s * 32 + cq * 8];
                acc0[mt] = __builtin_amdgcn_mfma_f32_16x16x32_bf16(
                    af, bfr0, acc0[mt], 0, 0, 0);
                acc1[mt] = __builtin_amdgcn_mfma_f32_16x16x32_bf16(
                    af, bfr1, acc1[mt], 0, 0, 0);
            }
        }
        __syncthreads();
    }

    // ---- epilogue: pool pairs via shfl, store bf16 ----
    #pragma unroll
    for (int wv = 0; wv < 2; ++wv) {
        short* fp = feat + (win0 + wv) * 2048;
        int iev = (w * 16 + cl) >> 1;
        #pragma unroll
        for (int mt = 0; mt < 4; ++mt) {
            #pragma unroll
            for (int rg = 0; rg < 4; ++rg) {
                float v = wv ? acc1[mt][rg] : acc0[mt][rg];
                float v2 = __shfl_xor(v, 1, 64);
                if ((cl & 1) == 0) {
                    int c = mt * 16 + cq * 4 + rg;
                    float pv = fmaxf(fmaxf(v, v2) + b2[c], 0.f);
                    fp[c * 32 + iev] = f2bf(pv);
                }
            }
        }
    }
}

// ---------------- bf16 MFMA GEMM (thin-N): BM=128, BN=64, double-buffered --
// EPI bits: 1=relu, 2=+resid(f32), 4=+pe, 8=write f32, 16=write bf16
template <int EPI>
__global__ __launch_bounds__(256) void gemm_bf16(
    const short* __restrict__ A, const short* __restrict__ Bt,
    const float* __restrict__ bias, const float* __restrict__ resid,
    const float* __restrict__ pe, float* __restrict__ outF,
    short* __restrict__ outB, int M, int N, int K)
{
    __shared__ short As[2][128 * 64];
    __shared__ short Bs[2][64 * 64];
    int tid = threadIdx.x;
    int w = tid >> 6, lane = tid & 63;
    int wm = w >> 1, wn = w & 1;
    int m0 = blockIdx.y * 128, n0 = blockIdx.x * 64;

    int rl = lane >> 3, sl = lane & 7;
    int cb = sl ^ rl;
    const short* aptr[4];
    const short* bptr[2];
    int arow[4], brow[2];
    #pragma unroll
    for (int l = 0; l < 4; ++l) {
        arow[l] = l * 32 + w * 8;
        aptr[l] = A + (size_t)(m0 + arow[l] + rl) * K + cb * 8;
    }
    #pragma unroll
    for (int l = 0; l < 2; ++l) {
        brow[l] = l * 32 + w * 8;
        bptr[l] = Bt + (size_t)(n0 + brow[l] + rl) * K + cb * 8;
    }

    int cq = lane >> 4, cl = lane & 15;
    f32x4 acc[4][2];
    #pragma unroll
    for (int mt = 0; mt < 4; ++mt)
        #pragma unroll
        for (int nt = 0; nt < 2; ++nt)
            acc[mt][nt] = (f32x4){0.f, 0.f, 0.f, 0.f};

    #pragma unroll
    for (int l = 0; l < 4; ++l) { gload_lds16(aptr[l], &As[0][arow[l] * 64]); aptr[l] += 64; }
    #pragma unroll
    for (int l = 0; l < 2; ++l) { gload_lds16(bptr[l], &Bs[0][brow[l] * 64]); bptr[l] += 64; }
    __syncthreads();

    int nk = K >> 6;
    for (int k = 0; k < nk; ++k) {
        int cur = k & 1;
        if (k + 1 < nk) {
            #pragma unroll
            for (int l = 0; l < 4; ++l) { gload_lds16(aptr[l], &As[cur ^ 1][arow[l] * 64]); aptr[l] += 64; }
            #pragma unroll
            for (int l = 0; l < 2; ++l) { gload_lds16(bptr[l], &Bs[cur ^ 1][brow[l] * 64]); bptr[l] += 64; }
        }
        #pragma unroll
        for (int s = 0; s < 2; ++s) {
            bf16x8 afr[4], bfr[2];
            #pragma unroll
            for (int mt = 0; mt < 4; ++mt) {
                int r = wm * 64 + mt * 16 + cl;
                int slot = (s * 4 + cq) ^ (r & 7);
                afr[mt] = *(const bf16x8*)&As[cur][r * 64 + slot * 8];
            }
            #pragma unroll
            for (int nt = 0; nt < 2; ++nt) {
                int r = wn * 32 + nt * 16 + cl;
                int slot = (s * 4 + cq) ^ (r & 7);
                bfr[nt] = *(const bf16x8*)&Bs[cur][r * 64 + slot * 8];
            }
            #pragma unroll
            for (int mt = 0; mt < 4; ++mt)
                #pragma unroll
                for (int nt = 0; nt < 2; ++nt)
                    acc[mt][nt] = __builtin_amdgcn_mfma_f32_16x16x32_bf16(
                        afr[mt], bfr[nt], acc[mt][nt], 0, 0, 0);
        }
        __syncthreads();
    }

    #pragma unroll
    for (int mt = 0; mt < 4; ++mt) {
        #pragma unroll
        for (int nt = 0; nt < 2; ++nt) {
            int col = n0 + wn * 32 + nt * 16 + cl;
            float bb = bias[col];
            #pragma unroll
            for (int rg = 0; rg < 4; ++rg) {
                int row = m0 + wm * 64 + mt * 16 + cq * 4 + rg;
                float v = acc[mt][nt][rg] + bb;
                if (EPI & 1) v = fmaxf(v, 0.f);
                if (EPI & 4) v += pe[(row & 127) * 384 + col];
                if (EPI & 2) v += resid[(size_t)row * N + col];
                if (EPI & 8) outF[(size_t)row * N + col] = v;
                if (EPI & 16) outB[(size_t)row * N + col] = f2bf(v);
            }
        }
    }
}

// ---------------- bf16 MFMA GEMM (wide-N): BM=128, BN=128, BK=32 dbuf ------
template <int EPI>
__global__ __launch_bounds__(256) void gemm_bf16_wide(
    const short* __restrict__ A, const short* __restrict__ Bt,
    const float* __restrict__ bias, float* __restrict__ outF,
    short* __restrict__ outB, int M, int N, int K)
{
    __shared__ short As[2][128 * 32];
    __shared__ short Bs[2][128 * 32];
    int tid = threadIdx.x;
    int w = tid >> 6, lane = tid & 63;
    int wm = w >> 1, wn = w & 1;
    int m0 = blockIdx.y * 128, n0 = blockIdx.x * 128;

    int rl = lane >> 2, sl = lane & 3;
    int cb = sl ^ (rl & 3) ^ ((rl >> 2) & 3);
    const short* aptr[2];
    const short* bptr[2];
    int srow[2];
    #pragma unroll
    for (int l = 0; l < 2; ++l) {
        srow[l] = w * 32 + l * 16;
        aptr[l] = A + (size_t)(m0 + srow[l] + rl) * K + cb * 8;
        bptr[l] = Bt + (size_t)(n0 + srow[l] + rl) * K + cb * 8;
    }

    int cq = lane >> 4, cl = lane & 15;
    f32x4 acc[4][4];
    #pragma unroll
    for (int mt = 0; mt < 4; ++mt)
        #pragma unroll
        for (int nt = 0; nt < 4; ++nt)
            acc[mt][nt] = (f32x4){0.f, 0.f, 0.f, 0.f};

    #pragma unroll
    for (int l = 0; l < 2; ++l) {
        gload_lds16(aptr[l], &As[0][srow[l] * 32]);
        gload_lds16(bptr[l], &Bs[0][srow[l] * 32]);
        aptr[l] += 32; bptr[l] += 32;
    }
    __syncthreads();

    int nk = K >> 5;
    for (int k = 0; k < nk; ++k) {
        int cur = k & 1;
        if (k + 1 < nk) {
            #pragma unroll
            for (int l = 0; l < 2; ++l) {
                gload_lds16(aptr[l], &As[cur ^ 1][srow[l] * 32]);
                gload_lds16(bptr[l], &Bs[cur ^ 1][srow[l] * 32]);
                aptr[l] += 32; bptr[l] += 32;
            }
        }
        bf16x8 afr[4], bfr[4];
        #pragma unroll
        for (int mt = 0; mt < 4; ++mt) {
            int r = wm * 64 + mt * 16 + cl;
            int slot = cq ^ (r & 3) ^ ((r >> 2) & 3);
            afr[mt] = *(const bf16x8*)&As[cur][r * 32 + slot * 8];
        }
        #pragma unroll
        for (int nt = 0; nt < 4; ++nt) {
            int r = wn * 64 + nt * 16 + cl;
            int slot = cq ^ (r & 3) ^ ((r >> 2) & 3);
            bfr[nt] = *(const bf16x8*)&Bs[cur][r * 32 + slot * 8];
        }
        #pragma unroll
        for (int mt = 0; mt < 4; ++mt)
            #pragma unroll
            for (int nt = 0; nt < 4; ++nt)
                acc[mt][nt] = __builtin_amdgcn_mfma_f32_16x16x32_bf16(
                    afr[mt], bfr[nt], acc[mt][nt], 0, 0, 0);
        __syncthreads();
    }

    #pragma unroll
    for (int mt = 0; mt < 4; ++mt) {
        #pragma unroll
        for (int nt = 0; nt < 4; ++nt) {
            int col = n0 + wn * 64 + nt * 16 + cl;
            float bb = bias[col];
            #pragma unroll
            for (int rg = 0; rg < 4; ++rg) {
                int row = m0 + wm * 64 + mt * 16 + cq * 4 + rg;
                float v = acc[mt][nt][rg] + bb;
                if (EPI & 1) v = fmaxf(v, 0.f);
                if (EPI & 8) outF[(size_t)row * N + col] = v;
                if (EPI & 16) outB[(size_t)row * N + col] = f2bf(v);
            }
        }
    }
}

// ---------------- fused GEMM + bias + residual + LayerNorm -----------------
// BM=16, BN=384, BK=64 -> grid 512. (BK=32 regressed in R13.)
__global__ __launch_bounds__(256) void gemm_ln(
    const short* __restrict__ A, const short* __restrict__ Bt,
    const float* __restrict__ bias, const float* resid,
    const float* __restrict__ g, const float* __restrict__ be,
    float* t, short* __restrict__ tb, int K)
{
    __shared__ __align__(16) char smem[51200];
    short* As = (short*)smem;              // 16 x 64 bf16 = 2 KB
    short* Bs = (short*)(smem + 2048);     // 384 x 64 bf16 = 48 KB

    int tid = threadIdx.x;
    int w = tid >> 6, lane = tid & 63;
    int m0 = blockIdx.x * 16;
    int rl = lane >> 3, sl = lane & 7;
    int cb = sl ^ rl;

    const short* aptr = A + (size_t)(m0 + w * 8 + rl) * K + cb * 8;
    const short* bptr[12];
    #pragma unroll
    for (int l = 0; l < 12; ++l)
        bptr[l] = Bt + (size_t)(w * 96 + l * 8 + rl) * K + cb * 8;

    int cq = lane >> 4, cl = lane & 15;
    f32x4 acc[6];
    #pragma unroll
    for (int nt = 0; nt < 6; ++nt) acc[nt] = (f32x4){0.f, 0.f, 0.f, 0.f};

    for (int k0 = 0; k0 < K; k0 += 64) {
        if (w < 2) {
            gload_lds16(aptr, &As[(w * 8) * 64]);
            aptr += 64;
        }
        #pragma unroll
        for (int l = 0; l < 12; ++l) {
            gload_lds16(bptr[l], &Bs[(w * 96 + l * 8) * 64]);
            bptr[l] += 64;
        }
        __syncthreads();
        #pragma unroll
        for (int s = 0; s < 2; ++s) {
            bf16x8 afr, bfr[6];
            {
                int r = cl;
                int slot = (s * 4 + cq) ^ (r & 7);
                afr = *(const bf16x8*)&As[r * 64 + slot * 8];
            }
            #pragma unroll
            for (int nt = 0; nt < 6; ++nt) {
                int r = w * 96 + nt * 16 + cl;
                int slot = (s * 4 + cq) ^ (r & 7);
                bfr[nt] = *(const bf16x8*)&Bs[r * 64 + slot * 8];
            }
            #pragma unroll
            for (int nt = 0; nt < 6; ++nt)
                acc[nt] = __builtin_amdgcn_mfma_f32_16x16x32_bf16(
                    afr, bfr[nt], acc[nt], 0, 0, 0);
        }
        __syncthreads();
    }

    // ---- epilogue: y = acc + bias + resid -> LDS (16 x 388 f32) ----
    float* yb = (float*)smem;
    #pragma unroll
    for (int nt = 0; nt < 6; ++nt) {
        int col = w * 96 + nt * 16 + cl;
        float bb = bias[col];
        #pragma unroll
        for (int rg = 0; rg < 4; ++rg) {
            int rloc = cq * 4 + rg;
            yb[rloc * 388 + col] =
                acc[nt][rg] + bb + resid[(size_t)(m0 + rloc) * 384 + col];
        }
    }
    __syncthreads();

    // ---- LayerNorm: 16 threads per row ----
    int rloc = tid >> 4, sub = tid & 15;
    f32x4 vals[6];
    float s = 0.f, s2 = 0.f;
    #pragma unroll
    for (int m = 0; m < 6; ++m) {
        f32x4 vv = *(const f32x4*)&yb[rloc * 388 + m * 64 + sub * 4];
        vals[m] = vv;
        #pragma unroll
        for (int j = 0; j < 4; ++j) {
            s += vv[j];
            s2 = fmaf(vv[j], vv[j], s2);
        }
    }
    s += __shfl_xor(s, 1, 64);  s2 += __shfl_xor(s2, 1, 64);
    s += __shfl_xor(s, 2, 64);  s2 += __shfl_xor(s2, 2, 64);
    s += __shfl_xor(s, 4, 64);  s2 += __shfl_xor(s2, 4, 64);
    s += __shfl_xor(s, 8, 64);  s2 += __shfl_xor(s2, 8, 64);
    float mean = s * (1.f / 384.f);
    float var = s2 * (1.f / 384.f) - mean * mean;
    float inv = rsqrtf(var + 1e-5f);

    size_t ro = (size_t)(m0 + rloc) * 384;
    #pragma unroll
    for (int m = 0; m < 6; ++m) {
        int c0 = m * 64 + sub * 4;
        f32x4 gg = *(const f32x4*)&g[c0];
        f32x4 bb = *(const f32x4*)&be[c0];
        f32x4 ov;
        s16x4 ob2;
        #pragma unroll
        for (int j = 0; j < 4; ++j) {
            float v = (vals[m][j] - mean) * inv * gg[j] + bb[j];
            ov[j] = v;
            ob2[j] = f2bf(v);
        }
        *(f32x4*)&t[ro + c0] = ov;
        *(s16x4*)&tb[ro + c0] = ob2;
    }
}

// ---------------- fused attention per (n,h): split-E x2, 256 threads -------
__global__ __launch_bounds__(256) void attn_kernel(
    const short* __restrict__ qkv, short* __restrict__ o)
{
    __shared__ f32x4 Ks[128][12];
    __shared__ f32x4 Vs[128][12];
    int tid = threadIdx.x;
    int n = blockIdx.x >> 3, h = blockIdx.x & 7;
    size_t base = (size_t)n * 128 * 1152 + (size_t)h * 48;
    const short* kp = qkv + base + 384;
    const short* vp = qkv + base + 768;
    for (int i = tid; i < 1536; i += 256) {
        int s = i / 12, e4 = i - s * 12;
        s16x4 kv = *(const s16x4*)(kp + (size_t)s * 1152 + e4 * 4);
        s16x4 vv = *(const s16x4*)(vp + (size_t)s * 1152 + e4 * 4);
        f32x4 kf, vf;
        #pragma unroll
        for (int j = 0; j < 4; ++j) { kf[j] = bf2f(kv[j]); vf[j] = bf2f(vv[j]); }
        Ks[s][e4] = kf;
        Vs[s][e4] = vf;
    }
    const float temp = 0.14433756729740643f;  // 1/sqrt(48)
    int r = tid >> 1;
    int h2 = tid & 1;
    int eb0 = h2 * 6;
    float qr[24];
    {
        const short* qp = qkv + base + (size_t)r * 1152 + h2 * 24;
        #pragma unroll
        for (int e4 = 0; e4 < 6; ++e4) {
            s16x4 qv = *(const s16x4*)(qp + e4 * 4);
            #pragma unroll
            for (int j = 0; j < 4; ++j) qr[e4 * 4 + j] = bf2f(qv[j]) * temp;
        }
    }
    __syncthreads();

    float m = -1e30f, denom = 0.f;
    f32x4 acc[6];
    #pragma unroll
    for (int e = 0; e < 6; ++e) acc[e] = (f32x4){0.f, 0.f, 0.f, 0.f};

    for (int s0 = 0; s0 < 128; s0 += 8) {
        float sc[8];
        #pragma unroll
        for (int u = 0; u < 8; ++u) {
            float t0 = 0.f;
            #pragma unroll
            for (int e = 0; e < 6; ++e) {
                f32x4 kk = Ks[s0 + u][eb0 + e];
                t0 = fmaf(qr[e * 4 + 0], kk[0], t0);
                t0 = fmaf(qr[e * 4 + 1], kk[1], t0);
                t0 = fmaf(qr[e * 4 + 2], kk[2], t0);
                t0 = fmaf(qr[e * 4 + 3], kk[3], t0);
            }
            sc[u] = t0 + __shfl_xor(t0, 1, 64);
        }
        float cmax = sc[0];
        #pragma unroll
        for (int u = 1; u < 8; ++u) cmax = fmaxf(cmax, sc[u]);
        float nm = fmaxf(m, cmax);
        float alpha = __expf(m - nm);
        m = nm;
        float p[8];
        float ps = 0.f;
        #pragma unroll
        for (int u = 0; u < 8; ++u) { p[u] = __expf(sc[u] - nm); ps += p[u]; }
        denom = denom * alpha + ps;
        #pragma unroll
        for (int e = 0; e < 6; ++e) {
            f32x4 a = acc[e];
            a[0] *= alpha; a[1] *= alpha; a[2] *= alpha; a[3] *= alpha;
            #pragma unroll
            for (int u = 0; u < 8; ++u) {
                f32x4 vv = Vs[s0 + u][eb0 + e];
                a[0] = fmaf(p[u], vv[0], a[0]);
                a[1] = fmaf(p[u], vv[1], a[1]);
                a[2] = fmaf(p[u], vv[2], a[2]);
                a[3] = fmaf(p[u], vv[3], a[3]);
            }
            acc[e] = a;
        }
    }
    float inv = 1.f / denom;
    short* op = o + ((size_t)n * 128 + r) * 384 + h * 48 + h2 * 24;
    #pragma unroll
    for (int e = 0; e < 6; ++e) {
        s16x4 ov;
        #pragma unroll
        for (int j = 0; j < 4; ++j) ov[j] = f2bf(acc[e][j] * inv);
        *(s16x4*)(op + e * 4) = ov;
    }
}

// ---------------- classifier head ------------------------------------------
__global__ __launch_bounds__(384) void head_kernel(
    const float* __restrict__ t, const float* __restrict__ cls_w,
    const float* __restrict__ cls_b, float* __restrict__ out)
{
    int n = blockIdx.x, d = threadIdx.x;
    float s = 0.f;
    for (int l = 0; l < 128; ++l) s += t[((size_t)n * 128 + l) * 384 + d];
    float p = s * (1.f / 128.f) * cls_w[d];
    #pragma unroll
    for (int off = 32; off > 0; off >>= 1) p += __shfl_xor(p, off, 64);
    __shared__ float red[6];
    if ((threadIdx.x & 63) == 0) red[threadIdx.x >> 6] = p;
    __syncthreads();
    if (threadIdx.x == 0) {
        float tot = red[0] + red[1] + red[2] + red[3] + red[4] + red[5];
        out[n] = tot + cls_b[0];
    }
}

// ---------------------------------------------------------------------------
extern "C" void kernel_launch(void* const* d_in, const int* in_sizes, int n_in,
                              void* d_out, int out_size, void* d_ws, size_t ws_size,
                              hipStream_t stream) {
    (void)n_in; (void)out_size; (void)ws_size;
    const float* x   = (const float*)d_in[0];
    const float* cw0 = (const float*)d_in[1];
    const float* cb0 = (const float*)d_in[2];
    const float* cw1 = (const float*)d_in[3];
    const float* cb1 = (const float*)d_in[4];
    const float* cw2 = (const float*)d_in[5];
    const float* cb2 = (const float*)d_in[6];
    const float* ew  = (const float*)d_in[7];
    const float* eb  = (const float*)d_in[8];
    bool dict_order = (in_sizes[10] == 589824);
    const float *Wq, *Wk, *Wv, *Wo, *W1, *W2, *bq, *bk, *bv, *bo, *b1, *b2;
    if (dict_order) {
        Wq = (const float*)d_in[9];  Wk = (const float*)d_in[10];
        Wv = (const float*)d_in[11]; Wo = (const float*)d_in[12];
        W1 = (const float*)d_in[13]; W2 = (const float*)d_in[14];
        bq = (const float*)d_in[15]; bk = (const float*)d_in[16];
        bv = (const float*)d_in[17]; bo = (const float*)d_in[18];
        b1 = (const float*)d_in[19]; b2 = (const float*)d_in[20];
    } else {
        Wq = (const float*)d_in[9];  bq = (const float*)d_in[10];
        Wk = (const float*)d_in[11]; bk = (const float*)d_in[12];
        Wv = (const float*)d_in[13]; bv = (const float*)d_in[14];
        Wo = (const float*)d_in[15]; bo = (const float*)d_in[16];
        W1 = (const float*)d_in[17]; b1 = (const float*)d_in[18];
        W2 = (const float*)d_in[19]; b2 = (const float*)d_in[20];
    }
    const float* g1  = (const float*)d_in[21];
    const float* be1 = (const float*)d_in[22];
    const float* g2  = (const float*)d_in[23];
    const float* be2 = (const float*)d_in[24];
    const float* clw = (const float*)d_in[25];
    const float* clb = (const float*)d_in[26];

    // ---- workspace layout (bytes) ----
    char* wp = (char*)d_ws;
    float* pe    = (float*)wp; wp += 196608;      // 128*384 f32
    short* featb = (short*)wp; wp += 33554432;    // 8192*2048 bf16 (reused as FFN hidden)
    float* t     = (float*)wp; wp += 12582912;    // 8192*384 f32
    short* tb    = (short*)wp; wp += 6291456;     // 8192*384 bf16
    short* qkvb  = (short*)wp; wp += 18874368;    // 8192*1152 bf16
    short* ob    = (short*)wp; wp += 6291456;     // 8192*384 bf16 (attn out)
    short* ewT   = (short*)wp; wp += 1572864;     // 384 x 2048
    short* WqkvT = (short*)wp; wp += 3538944;     // 4 x 1152 x 384
    short* WoT   = (short*)wp; wp += 1179648;     // 4 x 384 x 384
    short* W1T   = (short*)wp; wp += 4718592;     // 4 x 1536 x 384
    short* W2T   = (short*)wp; wp += 4718592;     // 4 x 384 x 1536
    float* bqkv  = (float*)wp; wp += 18432;       // 4 x 1152 f32
    short* w2T   = (short*)wp; wp += 16384;       // 64 x 128 bf16 (conv2)
    short* hb    = featb;                         // FFN hidden 8192*1536 bf16

    const int ROWS = 8192;

    pe_kernel<<<128, 384, 0, stream>>>(pe);
    wcvt_kernel<<<dim3(64, 12, 1), 256, 0, stream>>>(ew, ewT, 2048, 384, 0, 0, 0);
    qkvcvt_kernel<<<dim3(12, 12, 12), 256, 0, stream>>>(Wq, Wk, Wv, WqkvT);
    wcvt_kernel<<<dim3(12, 12, 4), 256, 0, stream>>>(Wo, WoT, 384, 384, 0, 147456, 147456);
    wcvt_kernel<<<dim3(12, 48, 4), 256, 0, stream>>>(W1, W1T, 384, 1536, 0, 589824, 589824);
    wcvt_kernel<<<dim3(48, 12, 4), 256, 0, stream>>>(W2, W2T, 1536, 384, 0, 589824, 589824);
    biascat_kernel<<<4, 384, 0, stream>>>(bq, bk, bv, bqkv);
    w2cvt_kernel<<<32, 256, 0, stream>>>(cw2, w2T);
    cnn_kernel<<<4096, 256, 0, stream>>>(x, cw0, cb0, cw1, cb1, w2T, cb2, featb);

    // t/tb = relu(feat @ ew + eb) + pe
    gemm_bf16<29><<<dim3(6, 64), 256, 0, stream>>>(featb, ewT, eb, nullptr, pe,
                                                   t, tb, ROWS, 384, 2048);
    for (int i = 0; i < 4; ++i) {
        const short* WqkvTi = WqkvT + (size_t)i * 442368;
        const short* WoTi = WoT + (size_t)i * 147456;
        const short* W1Ti = W1T + (size_t)i * 589824;
        const short* W2Ti = W2T + (size_t)i * 589824;
        gemm_bf16_wide<16><<<dim3(9, 64), 256, 0, stream>>>(tb, WqkvTi,
            bqkv + i * 1152, nullptr, qkvb, ROWS, 1152, 384);
        attn_kernel<<<512, 256, 0, stream>>>(qkvb, ob);
        // t/tb = LN(o @ Wo + bo + t)
        gemm_ln<<<512, 256, 0, stream>>>(ob, WoTi, bo + i * 384, t,
            g1 + i * 384, be1 + i * 384, t, tb, 384);
        // hidden = relu(t @ W1 + b1)
        gemm_bf16_wide<17><<<dim3(12, 64), 256, 0, stream>>>(tb, W1Ti,
            b1 + i * 1536, nullptr, hb, ROWS, 1536, 384);
        // t/tb = LN(hidden @ W2 + b2 + t)
        gemm_ln<<<512, 256, 0, stream>>>(hb, W2Ti, b2 + i * 384, t,
            g2 + i * 384, be2 + i * 384, t, tb, 1536);
    }
    head_kernel<<<64, 384, 0, stream>>>(t, clw, clb, (float*)d_out);
}